// Round 1
// baseline (1198.109 us; speedup 1.0000x reference)
//
#include <hip/hip_runtime.h>
#include <hip/hip_bf16.h>
#include <cstdint>

// ---------- helpers ----------
__device__ __forceinline__ float bf2f(unsigned short u) {
    return __uint_as_float(((unsigned)u) << 16);
}
__device__ __forceinline__ unsigned short f2bf(float x) {
    unsigned u = __float_as_uint(x);
    u += 0x7fffu + ((u >> 16) & 1u);   // round-to-nearest-even
    return (unsigned short)(u >> 16);
}
__device__ __forceinline__ float lrelu(float x) { return x >= 0.f ? x : 0.2f * x; }

// ---------- GEMM: [M,128] x [128,256] -> bf16 [M,256] ----------
// block 256 threads, tile M=64 x N=256, K chunked by 32.
__global__ __launch_bounds__(256) void gemm128x256(
    const float* __restrict__ A, const float* __restrict__ W,
    unsigned short* __restrict__ C, int M)
{
    __shared__ float As[32][68];    // [k][row], padded stride 68 (16B-aligned rows)
    __shared__ float Bs[32][256];   // [k][n]
    const int t = threadIdx.x;
    const int tx = t & 31, ty = t >> 5;   // tx: col group 0..31, ty: row group 0..7
    const int row0 = blockIdx.x * 64;

    float acc[8][8];
#pragma unroll
    for (int r = 0; r < 8; r++)
#pragma unroll
        for (int c = 0; c < 8; c++) acc[r][c] = 0.f;

#pragma unroll 1
    for (int kc = 0; kc < 128; kc += 32) {
        // stage A tile: 64 rows x 32 k
#pragma unroll
        for (int i = 0; i < 2; i++) {
            int idx = t + i * 256;
            int r = idx >> 3;
            int kq = (idx & 7) << 2;
            float4 v = make_float4(0.f, 0.f, 0.f, 0.f);
            int grow = row0 + r;
            if (grow < M) v = *(const float4*)(A + (size_t)grow * 128 + kc + kq);
            As[kq + 0][r] = v.x; As[kq + 1][r] = v.y;
            As[kq + 2][r] = v.z; As[kq + 3][r] = v.w;
        }
        // stage B tile: 32 k x 256 n
#pragma unroll
        for (int i = 0; i < 8; i++) {
            int idx = t + i * 256;
            int kk = idx >> 6;
            int n4 = (idx & 63) << 2;
            *(float4*)&Bs[kk][n4] = *(const float4*)(W + (size_t)(kc + kk) * 256 + n4);
        }
        __syncthreads();
#pragma unroll 8
        for (int k = 0; k < 32; k++) {
            float a[8], b[8];
            *(float4*)&a[0] = *(const float4*)&As[k][ty * 8];
            *(float4*)&a[4] = *(const float4*)&As[k][ty * 8 + 4];
            *(float4*)&b[0] = *(const float4*)&Bs[k][tx * 4];
            *(float4*)&b[4] = *(const float4*)&Bs[k][128 + tx * 4];
#pragma unroll
            for (int r = 0; r < 8; r++)
#pragma unroll
                for (int c = 0; c < 8; c++)
                    acc[r][c] = fmaf(a[r], b[c], acc[r][c]);
        }
        __syncthreads();
    }
#pragma unroll
    for (int r = 0; r < 8; r++) {
        int grow = row0 + ty * 8 + r;
        if (grow < M) {
            ushort4 o0, o1;
            o0.x = f2bf(acc[r][0]); o0.y = f2bf(acc[r][1]);
            o0.z = f2bf(acc[r][2]); o0.w = f2bf(acc[r][3]);
            o1.x = f2bf(acc[r][4]); o1.y = f2bf(acc[r][5]);
            o1.z = f2bf(acc[r][6]); o1.w = f2bf(acc[r][7]);
            *(ushort4*)(C + (size_t)grow * 256 + tx * 4) = o0;
            *(ushort4*)(C + (size_t)grow * 256 + 128 + tx * 4) = o1;
        }
    }
}

// ---------- row dots: el = <row_head, attn_l[head]>, er likewise ----------
// one wave per row; lane: head = lane>>5, 4 dims each
__global__ __launch_bounds__(256) void rowdot(
    const unsigned short* __restrict__ X, int M,
    const float* __restrict__ attn_l, const float* __restrict__ attn_r,
    float* __restrict__ el, float* __restrict__ er)
{
    int wid = (int)((blockIdx.x * (unsigned)blockDim.x + threadIdx.x) >> 6);
    int lane = threadIdx.x & 63;
    if (wid >= M) return;
    int head = lane >> 5;
    int o = (lane & 31) << 2;
    ushort4 xv = *(const ushort4*)(X + (size_t)wid * 256 + head * 128 + o);
    float x0 = bf2f(xv.x), x1 = bf2f(xv.y), x2 = bf2f(xv.z), x3 = bf2f(xv.w);
    float4 al = *(const float4*)(attn_l + head * 128 + o);
    float dl = x0 * al.x + x1 * al.y + x2 * al.z + x3 * al.w;
    float dr = 0.f;
    if (er) {
        float4 ar = *(const float4*)(attn_r + head * 128 + o);
        dr = x0 * ar.x + x1 * ar.y + x2 * ar.z + x3 * ar.w;
    }
#pragma unroll
    for (int off = 16; off >= 1; off >>= 1) {
        dl += __shfl_xor(dl, off);
        dr += __shfl_xor(dr, off);
    }
    if ((lane & 31) == 0) {
        el[(size_t)wid * 2 + head] = dl;
        if (er) er[(size_t)wid * 2 + head] = dr;
    }
}

// ---------- CSR build ----------
__global__ void hist_kernel(const int* __restrict__ dst, int* __restrict__ deg, int Nb) {
    int t = blockIdx.x * blockDim.x + threadIdx.x;
    if (t < Nb) atomicAdd(&deg[dst[t]], 1);
}

__global__ __launch_bounds__(1024) void scan1024(
    const int* __restrict__ deg, int* __restrict__ rowptr, int* __restrict__ wo, int n)
{
    __shared__ int wsum[16];
    int t = threadIdx.x, lane = t & 63, w = t >> 6;
    int carry = 0;
    for (int base = 0; base < n; base += 1024) {
        int i = base + t;
        int v = (i < n) ? deg[i] : 0;
        int x = v;
#pragma unroll
        for (int off = 1; off < 64; off <<= 1) {
            int y = __shfl_up(x, off);
            if (lane >= off) x += y;
        }
        if (lane == 63) wsum[w] = x;
        __syncthreads();
        if (w == 0) {
            int s = (lane < 16) ? wsum[lane] : 0;
#pragma unroll
            for (int off = 1; off < 16; off <<= 1) {
                int y = __shfl_up(s, off);
                if (lane >= off) s += y;
            }
            if (lane < 16) wsum[lane] = s;
        }
        __syncthreads();
        int wofs = (w > 0) ? wsum[w - 1] : 0;
        int incl = carry + wofs + x;
        if (i < n) { rowptr[i + 1] = incl; wo[i] = incl - v; }
        int total = wsum[15];
        __syncthreads();   // protect wsum before next chunk
        carry += total;
    }
    if (t == 0) rowptr[0] = 0;
}

__global__ void fill_kernel(const int* __restrict__ dst, int* __restrict__ wo,
                            int* __restrict__ bidx, int Nb) {
    int t = blockIdx.x * blockDim.x + threadIdx.x;
    if (t < Nb) {
        int d = dst[t];
        int p = atomicAdd(&wo[d], 1);
        bidx[p] = t;
    }
}

// ---------- aggregation: wave per atom ----------
__global__ __launch_bounds__(256) void aggregate(
    const unsigned short* __restrict__ h, const unsigned short* __restrict__ e,
    const unsigned short* __restrict__ u,
    const float* __restrict__ er, const float* __restrict__ elh,
    const float* __restrict__ ele, const float* __restrict__ elu,
    const int* __restrict__ rowptr, const int* __restrict__ bidx,
    const int* __restrict__ src, const int* __restrict__ gid,
    float* __restrict__ hm, int Na)
{
    int wid = (int)((blockIdx.x * (unsigned)blockDim.x + threadIdx.x) >> 6);
    int lane = threadIdx.x & 63;
    if (wid >= Na) return;
    const int a = wid;
    const float er0 = er[(size_t)a * 2], er1 = er[(size_t)a * 2 + 1];
    const int g = gid[a];
    const float eul0 = lrelu(elu[(size_t)g * 2] + er0);
    const float eul1 = lrelu(elu[(size_t)g * 2 + 1] + er1);
    float m0 = eul0, m1 = eul1;
    const int rb = rowptr[a], re = rowptr[a + 1];
    for (int i = rb; i < re; i++) {
        int b = bidx[i]; int s = src[b];
        float eh0 = lrelu(elh[(size_t)s * 2] + er0), eh1 = lrelu(elh[(size_t)s * 2 + 1] + er1);
        float ee0 = lrelu(ele[(size_t)b * 2] + er0), ee1 = lrelu(ele[(size_t)b * 2 + 1] + er1);
        m0 = fmaxf(m0, fmaxf(eh0, ee0));
        m1 = fmaxf(m1, fmaxf(eh1, ee1));
    }
    float es0 = __expf(eul0 - m0), es1 = __expf(eul1 - m1);
    const int head = lane >> 5;
    const int d4 = lane << 2;          // dims 0..255, head-major matches [H][OUT] layout
    float acc0, acc1, acc2, acc3;
    {
        float eu_sel = head ? es1 : es0;
        ushort4 uv = *(const ushort4*)(u + (size_t)g * 256 + d4);
        acc0 = eu_sel * bf2f(uv.x); acc1 = eu_sel * bf2f(uv.y);
        acc2 = eu_sel * bf2f(uv.z); acc3 = eu_sel * bf2f(uv.w);
    }
    for (int i = rb; i < re; i++) {
        int b = bidx[i]; int s = src[b];
        float eh0 = lrelu(elh[(size_t)s * 2] + er0), eh1 = lrelu(elh[(size_t)s * 2 + 1] + er1);
        float ee0 = lrelu(ele[(size_t)b * 2] + er0), ee1 = lrelu(ele[(size_t)b * 2 + 1] + er1);
        float xh0 = __expf(eh0 - m0), xh1 = __expf(eh1 - m1);
        float xe0 = __expf(ee0 - m0), xe1 = __expf(ee1 - m1);
        es0 += xh0 + xe0; es1 += xh1 + xe1;
        float wh = head ? xh1 : xh0;
        float we = head ? xe1 : xe0;
        ushort4 hv = *(const ushort4*)(h + (size_t)s * 256 + d4);
        ushort4 ev = *(const ushort4*)(e + (size_t)b * 256 + d4);
        acc0 += wh * bf2f(hv.x) + we * bf2f(ev.x);
        acc1 += wh * bf2f(hv.y) + we * bf2f(ev.y);
        acc2 += wh * bf2f(hv.z) + we * bf2f(ev.z);
        acc3 += wh * bf2f(hv.w) + we * bf2f(ev.w);
    }
    float inv = 1.f / (head ? es1 : es0);
    acc0 *= inv; acc1 *= inv; acc2 *= inv; acc3 *= inv;
    // mean over heads: lanes<32 combine with lane+32
    float p0 = __shfl(acc0, (lane + 32) & 63);
    float p1 = __shfl(acc1, (lane + 32) & 63);
    float p2 = __shfl(acc2, (lane + 32) & 63);
    float p3 = __shfl(acc3, (lane + 32) & 63);
    if (lane < 32) {
        float4 o = make_float4(0.5f * (acc0 + p0), 0.5f * (acc1 + p1),
                               0.5f * (acc2 + p2), 0.5f * (acc3 + p3));
        *(float4*)(hm + (size_t)a * 128 + d4) = o;
    }
}

// ---------- BatchNorm stats ----------
__global__ void bnstats(const float* __restrict__ hm, float* __restrict__ sums, int Na) {
    int t = threadIdx.x;
    int c = t & 127, half = t >> 7;
    float s = 0.f, ss = 0.f;
    for (int r = blockIdx.x * 2 + half; r < Na; r += gridDim.x * 2) {
        float v = hm[(size_t)r * 128 + c];
        s += v; ss += v * v;
    }
    atomicAdd(&sums[c], s);
    atomicAdd(&sums[128 + c], ss);
}

// ---------- BN normalize + ReLU ----------
__global__ void bnapply(const float* __restrict__ hm, const float* __restrict__ sums,
                        const float* __restrict__ gamma, const float* __restrict__ beta,
                        float* __restrict__ out, int Na) {
    int t = threadIdx.x;
    int c = t & 127, half = t >> 7;
    float invn = 1.f / (float)Na;
    float mean = sums[c] * invn;
    float var = sums[128 + c] * invn - mean * mean;
    float scale = gamma[c] * rsqrtf(var + 1e-5f);
    float shift = beta[c] - mean * scale;
    for (int r = blockIdx.x * 2 + half; r < Na; r += gridDim.x * 2) {
        float v = hm[(size_t)r * 128 + c] * scale + shift;
        out[(size_t)r * 128 + c] = fmaxf(v, 0.f);
    }
}

// ---------- launch ----------
extern "C" void kernel_launch(void* const* d_in, const int* in_sizes, int n_in,
                              void* d_out, int out_size, void* d_ws, size_t ws_size,
                              hipStream_t stream)
{
    const float* atom   = (const float*)d_in[0];
    const float* bondf  = (const float*)d_in[1];
    const float* globf  = (const float*)d_in[2];
    const float* Wa     = (const float*)d_in[3];
    const float* Wb     = (const float*)d_in[4];
    const float* Wg     = (const float*)d_in[5];
    const float* attn_l = (const float*)d_in[6];
    const float* attn_r = (const float*)d_in[7];
    const float* gamma  = (const float*)d_in[8];
    const float* beta   = (const float*)d_in[9];
    const int* src      = (const int*)d_in[10];
    const int* dst      = (const int*)d_in[11];
    const int* gid      = (const int*)d_in[12];
    const int Na = in_sizes[0] / 128;
    const int Nb = in_sizes[1] / 128;
    const int Ng = in_sizes[2] / 128;

    char* w = (char*)d_ws;
    size_t off = 0;
    auto alloc = [&](size_t bytes) -> void* {
        void* p = w + off;
        off = (off + bytes + 255) & ~(size_t)255;
        return p;
    };
    unsigned short* h  = (unsigned short*)alloc((size_t)Na * 256 * 2);
    unsigned short* e  = (unsigned short*)alloc((size_t)Nb * 256 * 2);
    unsigned short* u  = (unsigned short*)alloc((size_t)Ng * 256 * 2);
    float* er   = (float*)alloc((size_t)Na * 2 * 4);
    float* elh  = (float*)alloc((size_t)Na * 2 * 4);
    float* ele  = (float*)alloc((size_t)Nb * 2 * 4);
    float* elu  = (float*)alloc((size_t)Ng * 2 * 4);
    int* deg    = (int*)alloc((size_t)Na * 4);
    int* rowptr = (int*)alloc((size_t)(Na + 1) * 4);
    int* wo     = (int*)alloc((size_t)Na * 4);
    int* bidx   = (int*)alloc((size_t)Nb * 4);
    float* hm   = (float*)alloc((size_t)Na * 128 * 4);
    float* sums = (float*)alloc(256 * 4);

    hipMemsetAsync(deg, 0, (size_t)Na * 4, stream);
    hipMemsetAsync(sums, 0, 256 * 4, stream);

    gemm128x256<<<(Na + 63) / 64, 256, 0, stream>>>(atom, Wa, h, Na);
    gemm128x256<<<(Nb + 63) / 64, 256, 0, stream>>>(bondf, Wb, e, Nb);
    gemm128x256<<<(Ng + 63) / 64, 256, 0, stream>>>(globf, Wg, u, Ng);

    rowdot<<<(Na + 3) / 4, 256, 0, stream>>>(h, Na, attn_l, attn_r, elh, er);
    rowdot<<<(Nb + 3) / 4, 256, 0, stream>>>(e, Nb, attn_l, nullptr, ele, nullptr);
    rowdot<<<(Ng + 3) / 4, 256, 0, stream>>>(u, Ng, attn_l, nullptr, elu, nullptr);

    hist_kernel<<<(Nb + 255) / 256, 256, 0, stream>>>(dst, deg, Nb);
    scan1024<<<1, 1024, 0, stream>>>(deg, rowptr, wo, Na);
    fill_kernel<<<(Nb + 255) / 256, 256, 0, stream>>>(dst, wo, bidx, Nb);

    aggregate<<<(Na + 3) / 4, 256, 0, stream>>>(h, e, u, er, elh, ele, elu,
                                                rowptr, bidx, src, gid, hm, Na);
    bnstats<<<256, 256, 0, stream>>>(hm, sums, Na);
    bnapply<<<512, 256, 0, stream>>>(hm, sums, gamma, beta, (float*)d_out, Na);
}

// Round 3
// 916.197 us; speedup vs baseline: 1.3077x; 1.3077x over previous
//
#include <hip/hip_runtime.h>
#include <hip/hip_bf16.h>
#include <cstdint>

typedef __attribute__((ext_vector_type(8))) short bf16x8;
typedef __attribute__((ext_vector_type(4))) float f32x4;

// ---------- helpers ----------
__device__ __forceinline__ float bf2f(unsigned short u) {
    return __uint_as_float(((unsigned)u) << 16);
}
__device__ __forceinline__ unsigned short f2bf(float x) {
    unsigned u = __float_as_uint(x);
    u += 0x7fffu + ((u >> 16) & 1u);   // round-to-nearest-even
    return (unsigned short)(u >> 16);
}
__device__ __forceinline__ float lrelu(float x) { return x >= 0.f ? x : 0.2f * x; }

// ---------- pack W [128,256] fp32 -> bf16 B-fragment layout ----------
// b-frag for (kk, n, quad): B[kk*32+quad*8+j][n], j=0..7 contiguous.
// packed elem index = ((kk*256 + n)*4 + quad)*8 + j   (quad stride 4 — injective!)
__global__ void packW(const float* __restrict__ W, unsigned short* __restrict__ Wp) {
    int idx = blockIdx.x * 256 + threadIdx.x;   // 32768 total
    int k = idx >> 8, n = idx & 255;
    int kk = k >> 5, r = k & 31, quad = r >> 3, j = r & 7;
    Wp[(((kk << 8) + n) * 4 + quad) * 8 + j] = f2bf(W[idx]);
}

// ---------- MFMA GEMM: [M,128]fp32 x [128,256] -> bf16 [M,256] + fused rowdots ----------
// block 256 threads = 4 waves; tile 64 rows x 256 cols; K=128 in one shot.
__global__ __launch_bounds__(256) void gemm_mfma(
    const float* __restrict__ A, const unsigned short* __restrict__ Wp,
    unsigned short* __restrict__ C, int M,
    const float* __restrict__ attn_l, const float* __restrict__ attn_r,
    float* __restrict__ el, float* __restrict__ er)
{
    __shared__ unsigned short lds[16896];   // union: A-stage 64x136 (8704) / C-bounce 64x264 (16896)
    const int t = threadIdx.x;
    const int row0 = blockIdx.x * 64;

    // ---- stage A: 64 rows x 128 fp32 -> bf16 LDS [64][136] ----
#pragma unroll
    for (int i = 0; i < 8; i++) {
        int flat = i * 4096 + t * 16;           // byte offset in 64x512B fp32 tile
        int row = flat >> 9;
        int colf = (flat & 511) >> 2;           // float index 0..127 (multiple of 4)
        float4 v = make_float4(0.f, 0.f, 0.f, 0.f);
        if (row0 + row < M) v = *(const float4*)(A + (size_t)(row0 + row) * 128 + colf);
        unsigned u0 = (unsigned)f2bf(v.x) | ((unsigned)f2bf(v.y) << 16);
        unsigned u1 = (unsigned)f2bf(v.z) | ((unsigned)f2bf(v.w) << 16);
        *(uint2*)(&lds[row * 136 + colf]) = make_uint2(u0, u1);
    }
    __syncthreads();

    // ---- MFMA: wave w computes rows 0..63 x cols w*64..w*64+63 ----
    const int w = t >> 6, lane = t & 63;
    const int quad = lane >> 4, l16 = lane & 15;
    const int col0w = w * 64;

    f32x4 acc[4][4];
#pragma unroll
    for (int rt = 0; rt < 4; rt++)
#pragma unroll
        for (int ct = 0; ct < 4; ct++) acc[rt][ct] = (f32x4)(0.f);

#pragma unroll
    for (int kk = 0; kk < 4; kk++) {
        bf16x8 af[4], bf[4];
#pragma unroll
        for (int rt = 0; rt < 4; rt++)
            af[rt] = *(const bf16x8*)(&lds[(rt * 16 + l16) * 136 + kk * 32 + quad * 8]);
#pragma unroll
        for (int ct = 0; ct < 4; ct++) {
            int n = col0w + ct * 16 + l16;
            bf[ct] = *(const bf16x8*)(Wp + ((((kk << 8) + n) * 4 + quad) << 3));
        }
#pragma unroll
        for (int rt = 0; rt < 4; rt++)
#pragma unroll
            for (int ct = 0; ct < 4; ct++)
                acc[rt][ct] = __builtin_amdgcn_mfma_f32_16x16x32_bf16(af[rt], bf[ct], acc[rt][ct], 0, 0, 0);
    }
    __syncthreads();   // A-stage LDS dead; reuse as C bounce

    // ---- bounce C to LDS [64][264] bf16 (C/D layout: col=lane&15, row=quad*4+reg) ----
#pragma unroll
    for (int rt = 0; rt < 4; rt++)
#pragma unroll
        for (int ct = 0; ct < 4; ct++) {
#pragma unroll
            for (int r = 0; r < 4; r++) {
                int row = rt * 16 + quad * 4 + r;
                int col = col0w + ct * 16 + l16;
                lds[row * 264 + col] = f2bf(acc[rt][ct][r]);
            }
        }
    __syncthreads();

    // ---- coalesced store + fused attn dots ----
#pragma unroll
    for (int i = 0; i < 8; i++) {
        int flat = i * 4096 + t * 16;           // byte offset in 64x512B bf16 C tile
        int row = flat >> 9;
        int cb = flat & 511;                     // byte within row (multiple of 16)
        uint4 v = *(const uint4*)((const char*)lds + row * 528 + cb);
        int grow = row0 + row;
        bool valid = grow < M;
        if (valid) *(uint4*)((char*)C + (size_t)grow * 512 + cb) = v;

        // dot with attn vectors: channels ch..ch+7, all within one head
        int ch = cb >> 1;
        float x0 = bf2f((unsigned short)(v.x & 0xffff)), x1 = bf2f((unsigned short)(v.x >> 16));
        float x2 = bf2f((unsigned short)(v.y & 0xffff)), x3 = bf2f((unsigned short)(v.y >> 16));
        float x4 = bf2f((unsigned short)(v.z & 0xffff)), x5 = bf2f((unsigned short)(v.z >> 16));
        float x6 = bf2f((unsigned short)(v.w & 0xffff)), x7 = bf2f((unsigned short)(v.w >> 16));
        float4 al0 = *(const float4*)(attn_l + ch);
        float4 al1 = *(const float4*)(attn_l + ch + 4);
        float dl = x0 * al0.x + x1 * al0.y + x2 * al0.z + x3 * al0.w
                 + x4 * al1.x + x5 * al1.y + x6 * al1.z + x7 * al1.w;
        float dr = 0.f;
        if (er) {
            float4 ar0 = *(const float4*)(attn_r + ch);
            float4 ar1 = *(const float4*)(attn_r + ch + 4);
            dr = x0 * ar0.x + x1 * ar0.y + x2 * ar0.z + x3 * ar0.w
               + x4 * ar1.x + x5 * ar1.y + x6 * ar1.z + x7 * ar1.w;
        }
#pragma unroll
        for (int off = 8; off >= 1; off >>= 1) {
            dl += __shfl_xor(dl, off);
            dr += __shfl_xor(dr, off);
        }
        if ((t & 15) == 0 && valid) {
            int head = (ch >> 7) & 1;
            el[(size_t)grow * 2 + head] = dl;
            if (er) er[(size_t)grow * 2 + head] = dr;
        }
    }
}

// ---------- CSR build ----------
__global__ void hist_kernel(const int* __restrict__ dst, int* __restrict__ deg, int Nb) {
    int t = blockIdx.x * blockDim.x + threadIdx.x;
    if (t < Nb) atomicAdd(&deg[dst[t]], 1);
}

__global__ __launch_bounds__(1024) void scan1024(
    const int* __restrict__ deg, int* __restrict__ rowptr, int* __restrict__ wo, int n)
{
    __shared__ int wsum[16];
    int t = threadIdx.x, lane = t & 63, w = t >> 6;
    int carry = 0;
    for (int base = 0; base < n; base += 1024) {
        int i = base + t;
        int v = (i < n) ? deg[i] : 0;
        int x = v;
#pragma unroll
        for (int off = 1; off < 64; off <<= 1) {
            int y = __shfl_up(x, off);
            if (lane >= off) x += y;
        }
        if (lane == 63) wsum[w] = x;
        __syncthreads();
        if (w == 0) {
            int s = (lane < 16) ? wsum[lane] : 0;
#pragma unroll
            for (int off = 1; off < 16; off <<= 1) {
                int y = __shfl_up(s, off);
                if (lane >= off) s += y;
            }
            if (lane < 16) wsum[lane] = s;
        }
        __syncthreads();
        int wofs = (w > 0) ? wsum[w - 1] : 0;
        int incl = carry + wofs + x;
        if (i < n) { rowptr[i + 1] = incl; wo[i] = incl - v; }
        int total = wsum[15];
        __syncthreads();
        carry += total;
    }
    if (t == 0) rowptr[0] = 0;
}

__global__ void fill_kernel(const int* __restrict__ dst, int* __restrict__ wo,
                            int* __restrict__ bidx, int Nb) {
    int t = blockIdx.x * blockDim.x + threadIdx.x;
    if (t < Nb) {
        int d = dst[t];
        int p = atomicAdd(&wo[d], 1);
        bidx[p] = t;
    }
}

// ---------- aggregation: wave per atom ----------
__global__ __launch_bounds__(256) void aggregate(
    const unsigned short* __restrict__ h, const unsigned short* __restrict__ e,
    const unsigned short* __restrict__ u,
    const float* __restrict__ er, const float* __restrict__ elh,
    const float* __restrict__ ele, const float* __restrict__ elu,
    const int* __restrict__ rowptr, const int* __restrict__ bidx,
    const int* __restrict__ src, const int* __restrict__ gid,
    float* __restrict__ hm, int Na)
{
    int wid = (int)((blockIdx.x * (unsigned)blockDim.x + threadIdx.x) >> 6);
    int lane = threadIdx.x & 63;
    if (wid >= Na) return;
    const int a = wid;
    const float er0 = er[(size_t)a * 2], er1 = er[(size_t)a * 2 + 1];
    const int g = gid[a];
    const float eul0 = lrelu(elu[(size_t)g * 2] + er0);
    const float eul1 = lrelu(elu[(size_t)g * 2 + 1] + er1);
    float m0 = eul0, m1 = eul1;
    const int rb = rowptr[a], re = rowptr[a + 1];
    for (int i = rb; i < re; i++) {
        int b = bidx[i]; int s = src[b];
        float eh0 = lrelu(elh[(size_t)s * 2] + er0), eh1 = lrelu(elh[(size_t)s * 2 + 1] + er1);
        float ee0 = lrelu(ele[(size_t)b * 2] + er0), ee1 = lrelu(ele[(size_t)b * 2 + 1] + er1);
        m0 = fmaxf(m0, fmaxf(eh0, ee0));
        m1 = fmaxf(m1, fmaxf(ee1, eh1));
    }
    float es0 = __expf(eul0 - m0), es1 = __expf(eul1 - m1);
    const int head = lane >> 5;
    const int d4 = lane << 2;
    float acc0, acc1, acc2, acc3;
    {
        float eu_sel = head ? es1 : es0;
        ushort4 uv = *(const ushort4*)(u + (size_t)g * 256 + d4);
        acc0 = eu_sel * bf2f(uv.x); acc1 = eu_sel * bf2f(uv.y);
        acc2 = eu_sel * bf2f(uv.z); acc3 = eu_sel * bf2f(uv.w);
    }
    for (int i = rb; i < re; i++) {
        int b = bidx[i]; int s = src[b];
        float eh0 = lrelu(elh[(size_t)s * 2] + er0), eh1 = lrelu(elh[(size_t)s * 2 + 1] + er1);
        float ee0 = lrelu(ele[(size_t)b * 2] + er0), ee1 = lrelu(ele[(size_t)b * 2 + 1] + er1);
        float xh0 = __expf(eh0 - m0), xh1 = __expf(eh1 - m1);
        float xe0 = __expf(ee0 - m0), xe1 = __expf(ee1 - m1);
        es0 += xh0 + xe0; es1 += xh1 + xe1;
        float wh = head ? xh1 : xh0;
        float we = head ? xe1 : xe0;
        ushort4 hv = *(const ushort4*)(h + (size_t)s * 256 + d4);
        ushort4 ev = *(const ushort4*)(e + (size_t)b * 256 + d4);
        acc0 += wh * bf2f(hv.x) + we * bf2f(ev.x);
        acc1 += wh * bf2f(hv.y) + we * bf2f(ev.y);
        acc2 += wh * bf2f(hv.z) + we * bf2f(ev.z);
        acc3 += wh * bf2f(hv.w) + we * bf2f(ev.w);
    }
    float inv = 1.f / (head ? es1 : es0);
    acc0 *= inv; acc1 *= inv; acc2 *= inv; acc3 *= inv;
    float p0 = __shfl(acc0, (lane + 32) & 63);
    float p1 = __shfl(acc1, (lane + 32) & 63);
    float p2 = __shfl(acc2, (lane + 32) & 63);
    float p3 = __shfl(acc3, (lane + 32) & 63);
    if (lane < 32) {
        float4 o = make_float4(0.5f * (acc0 + p0), 0.5f * (acc1 + p1),
                               0.5f * (acc2 + p2), 0.5f * (acc3 + p3));
        *(float4*)(hm + (size_t)a * 128 + d4) = o;
    }
}

// ---------- BatchNorm stats ----------
__global__ void bnstats(const float* __restrict__ hm, float* __restrict__ sums, int Na) {
    int t = threadIdx.x;
    int c = t & 127, half = t >> 7;
    float s = 0.f, ss = 0.f;
    for (int r = blockIdx.x * 2 + half; r < Na; r += gridDim.x * 2) {
        float v = hm[(size_t)r * 128 + c];
        s += v; ss += v * v;
    }
    atomicAdd(&sums[c], s);
    atomicAdd(&sums[128 + c], ss);
}

// ---------- BN normalize + ReLU ----------
__global__ void bnapply(const float* __restrict__ hm, const float* __restrict__ sums,
                        const float* __restrict__ gamma, const float* __restrict__ beta,
                        float* __restrict__ out, int Na) {
    int t = threadIdx.x;
    int c = t & 127, half = t >> 7;
    float invn = 1.f / (float)Na;
    float mean = sums[c] * invn;
    float var = sums[128 + c] * invn - mean * mean;
    float scale = gamma[c] * rsqrtf(var + 1e-5f);
    float shift = beta[c] - mean * scale;
    for (int r = blockIdx.x * 2 + half; r < Na; r += gridDim.x * 2) {
        float v = hm[(size_t)r * 128 + c] * scale + shift;
        out[(size_t)r * 128 + c] = fmaxf(v, 0.f);
    }
}

// ---------- launch ----------
extern "C" void kernel_launch(void* const* d_in, const int* in_sizes, int n_in,
                              void* d_out, int out_size, void* d_ws, size_t ws_size,
                              hipStream_t stream)
{
    const float* atom   = (const float*)d_in[0];
    const float* bondf  = (const float*)d_in[1];
    const float* globf  = (const float*)d_in[2];
    const float* Wa     = (const float*)d_in[3];
    const float* Wb     = (const float*)d_in[4];
    const float* Wg     = (const float*)d_in[5];
    const float* attn_l = (const float*)d_in[6];
    const float* attn_r = (const float*)d_in[7];
    const float* gamma  = (const float*)d_in[8];
    const float* beta   = (const float*)d_in[9];
    const int* src      = (const int*)d_in[10];
    const int* dst      = (const int*)d_in[11];
    const int* gid      = (const int*)d_in[12];
    const int Na = in_sizes[0] / 128;
    const int Nb = in_sizes[1] / 128;
    const int Ng = in_sizes[2] / 128;

    char* w = (char*)d_ws;
    size_t off = 0;
    auto alloc = [&](size_t bytes) -> void* {
        void* p = w + off;
        off = (off + bytes + 255) & ~(size_t)255;
        return p;
    };
    unsigned short* h   = (unsigned short*)alloc((size_t)Na * 256 * 2);
    unsigned short* e   = (unsigned short*)alloc((size_t)Nb * 256 * 2);
    unsigned short* u   = (unsigned short*)alloc((size_t)Ng * 256 * 2);
    unsigned short* Wpa = (unsigned short*)alloc(32768 * 2);
    unsigned short* Wpb = (unsigned short*)alloc(32768 * 2);
    unsigned short* Wpg = (unsigned short*)alloc(32768 * 2);
    float* er   = (float*)alloc((size_t)Na * 2 * 4);
    float* elh  = (float*)alloc((size_t)Na * 2 * 4);
    float* ele  = (float*)alloc((size_t)Nb * 2 * 4);
    float* elu  = (float*)alloc((size_t)Ng * 2 * 4);
    int* deg    = (int*)alloc((size_t)Na * 4);
    int* rowptr = (int*)alloc((size_t)(Na + 1) * 4);
    int* wo     = (int*)alloc((size_t)Na * 4);
    int* bidx   = (int*)alloc((size_t)Nb * 4);
    float* hm   = (float*)alloc((size_t)Na * 128 * 4);
    float* sums = (float*)alloc(256 * 4);

    hipMemsetAsync(deg, 0, (size_t)Na * 4, stream);
    hipMemsetAsync(sums, 0, 256 * 4, stream);

    packW<<<128, 256, 0, stream>>>(Wa, Wpa);
    packW<<<128, 256, 0, stream>>>(Wb, Wpb);
    packW<<<128, 256, 0, stream>>>(Wg, Wpg);

    gemm_mfma<<<(Na + 63) / 64, 256, 0, stream>>>(atom, Wpa, h, Na, attn_l, attn_r, elh, er);
    gemm_mfma<<<(Nb + 63) / 64, 256, 0, stream>>>(bondf, Wpb, e, Nb, attn_l, nullptr, ele, nullptr);
    gemm_mfma<<<(Ng + 63) / 64, 256, 0, stream>>>(globf, Wpg, u, Ng, attn_l, nullptr, elu, nullptr);

    hist_kernel<<<(Nb + 255) / 256, 256, 0, stream>>>(dst, deg, Nb);
    scan1024<<<1, 1024, 0, stream>>>(deg, rowptr, wo, Na);
    fill_kernel<<<(Nb + 255) / 256, 256, 0, stream>>>(dst, wo, bidx, Nb);

    aggregate<<<(Na + 3) / 4, 256, 0, stream>>>(h, e, u, er, elh, ele, elu,
                                                rowptr, bidx, src, gid, hm, Na);
    bnstats<<<256, 256, 0, stream>>>(hm, sums, Na);
    bnapply<<<512, 256, 0, stream>>>(hm, sums, gamma, beta, (float*)d_out, Na);
}

// Round 4
// 815.093 us; speedup vs baseline: 1.4699x; 1.1240x over previous
//
#include <hip/hip_runtime.h>
#include <hip/hip_bf16.h>
#include <cstdint>

typedef __attribute__((ext_vector_type(8))) short bf16x8;
typedef __attribute__((ext_vector_type(4))) float f32x4;

// ---------- helpers ----------
__device__ __forceinline__ float bf2f(unsigned short u) {
    return __uint_as_float(((unsigned)u) << 16);
}
__device__ __forceinline__ unsigned short f2bf(float x) {
    unsigned u = __float_as_uint(x);
    u += 0x7fffu + ((u >> 16) & 1u);   // round-to-nearest-even
    return (unsigned short)(u >> 16);
}
__device__ __forceinline__ float lrelu(float x) { return x >= 0.f ? x : 0.2f * x; }

// ---------- pack W [128,256] fp32 -> bf16 B-fragment layout ----------
// b-frag for (kk, n, quad): B[kk*32+quad*8+j][n], j=0..7 contiguous.
// packed elem index = ((kk*256 + n)*4 + quad)*8 + j   (quad stride 4 — injective)
__global__ void packW(const float* __restrict__ W, unsigned short* __restrict__ Wp) {
    int idx = blockIdx.x * 256 + threadIdx.x;   // 32768 total
    int k = idx >> 8, n = idx & 255;
    int kk = k >> 5, r = k & 31, quad = r >> 3, j = r & 7;
    Wp[(((kk << 8) + n) * 4 + quad) * 8 + j] = f2bf(W[idx]);
}

// ---------- MFMA GEMM: [M,128]fp32 x [128,256] -> bf16 [M,256] + fused rowdots ----------
__global__ __launch_bounds__(256) void gemm_mfma(
    const float* __restrict__ A, const unsigned short* __restrict__ Wp,
    unsigned short* __restrict__ C, int M,
    const float* __restrict__ attn_l, const float* __restrict__ attn_r,
    float* __restrict__ el, float* __restrict__ er)
{
    __shared__ unsigned short lds[16896];   // union: A-stage 64x136 (8704) / C-bounce 64x264 (16896)
    const int t = threadIdx.x;
    const int row0 = blockIdx.x * 64;

    // ---- stage A: 64 rows x 128 fp32 -> bf16 LDS [64][136] ----
#pragma unroll
    for (int i = 0; i < 8; i++) {
        int flat = i * 4096 + t * 16;           // byte offset in 64x512B fp32 tile
        int row = flat >> 9;
        int colf = (flat & 511) >> 2;
        float4 v = make_float4(0.f, 0.f, 0.f, 0.f);
        if (row0 + row < M) v = *(const float4*)(A + (size_t)(row0 + row) * 128 + colf);
        unsigned u0 = (unsigned)f2bf(v.x) | ((unsigned)f2bf(v.y) << 16);
        unsigned u1 = (unsigned)f2bf(v.z) | ((unsigned)f2bf(v.w) << 16);
        *(uint2*)(&lds[row * 136 + colf]) = make_uint2(u0, u1);
    }
    __syncthreads();

    const int w = t >> 6, lane = t & 63;
    const int quad = lane >> 4, l16 = lane & 15;
    const int col0w = w * 64;

    f32x4 acc[4][4];
#pragma unroll
    for (int rt = 0; rt < 4; rt++)
#pragma unroll
        for (int ct = 0; ct < 4; ct++) acc[rt][ct] = (f32x4)(0.f);

#pragma unroll
    for (int kk = 0; kk < 4; kk++) {
        bf16x8 af[4], bf[4];
#pragma unroll
        for (int rt = 0; rt < 4; rt++)
            af[rt] = *(const bf16x8*)(&lds[(rt * 16 + l16) * 136 + kk * 32 + quad * 8]);
#pragma unroll
        for (int ct = 0; ct < 4; ct++) {
            int n = col0w + ct * 16 + l16;
            bf[ct] = *(const bf16x8*)(Wp + ((((kk << 8) + n) * 4 + quad) << 3));
        }
#pragma unroll
        for (int rt = 0; rt < 4; rt++)
#pragma unroll
            for (int ct = 0; ct < 4; ct++)
                acc[rt][ct] = __builtin_amdgcn_mfma_f32_16x16x32_bf16(af[rt], bf[ct], acc[rt][ct], 0, 0, 0);
    }
    __syncthreads();

    // ---- bounce C to LDS [64][264] bf16 (C/D layout: col=lane&15, row=quad*4+reg) ----
#pragma unroll
    for (int rt = 0; rt < 4; rt++)
#pragma unroll
        for (int ct = 0; ct < 4; ct++) {
#pragma unroll
            for (int r = 0; r < 4; r++) {
                int row = rt * 16 + quad * 4 + r;
                int col = col0w + ct * 16 + l16;
                lds[row * 264 + col] = f2bf(acc[rt][ct][r]);
            }
        }
    __syncthreads();

    // ---- coalesced store + fused attn dots ----
#pragma unroll
    for (int i = 0; i < 8; i++) {
        int flat = i * 4096 + t * 16;
        int row = flat >> 9;
        int cb = flat & 511;
        uint4 v = *(const uint4*)((const char*)lds + row * 528 + cb);
        int grow = row0 + row;
        bool valid = grow < M;
        if (valid) *(uint4*)((char*)C + (size_t)grow * 512 + cb) = v;

        int ch = cb >> 1;
        float x0 = bf2f((unsigned short)(v.x & 0xffff)), x1 = bf2f((unsigned short)(v.x >> 16));
        float x2 = bf2f((unsigned short)(v.y & 0xffff)), x3 = bf2f((unsigned short)(v.y >> 16));
        float x4 = bf2f((unsigned short)(v.z & 0xffff)), x5 = bf2f((unsigned short)(v.z >> 16));
        float x6 = bf2f((unsigned short)(v.w & 0xffff)), x7 = bf2f((unsigned short)(v.w >> 16));
        float4 al0 = *(const float4*)(attn_l + ch);
        float4 al1 = *(const float4*)(attn_l + ch + 4);
        float dl = x0 * al0.x + x1 * al0.y + x2 * al0.z + x3 * al0.w
                 + x4 * al1.x + x5 * al1.y + x6 * al1.z + x7 * al1.w;
        float dr = 0.f;
        if (er) {
            float4 ar0 = *(const float4*)(attn_r + ch);
            float4 ar1 = *(const float4*)(attn_r + ch + 4);
            dr = x0 * ar0.x + x1 * ar0.y + x2 * ar0.z + x3 * ar0.w
               + x4 * ar1.x + x5 * ar1.y + x6 * ar1.z + x7 * ar1.w;
        }
#pragma unroll
        for (int off = 8; off >= 1; off >>= 1) {
            dl += __shfl_xor(dl, off);
            dr += __shfl_xor(dr, off);
        }
        if ((t & 15) == 0 && valid) {
            int head = (ch >> 7) & 1;
            el[(size_t)grow * 2 + head] = dl;
            if (er) er[(size_t)grow * 2 + head] = dr;
        }
    }
}

// ---------- CSR build ----------
__global__ void hist_kernel(const int* __restrict__ dst, int* __restrict__ deg, int Nb) {
    int t = blockIdx.x * blockDim.x + threadIdx.x;
    if (t < Nb) atomicAdd(&deg[dst[t]], 1);
}

__global__ __launch_bounds__(1024) void scan1024(
    const int* __restrict__ deg, int* __restrict__ rowptr, int* __restrict__ wo, int n)
{
    __shared__ int wsum[16];
    int t = threadIdx.x, lane = t & 63, w = t >> 6;
    int carry = 0;
    for (int base = 0; base < n; base += 1024) {
        int i = base + t;
        int v = (i < n) ? deg[i] : 0;
        int x = v;
#pragma unroll
        for (int off = 1; off < 64; off <<= 1) {
            int y = __shfl_up(x, off);
            if (lane >= off) x += y;
        }
        if (lane == 63) wsum[w] = x;
        __syncthreads();
        if (w == 0) {
            int s = (lane < 16) ? wsum[lane] : 0;
#pragma unroll
            for (int off = 1; off < 16; off <<= 1) {
                int y = __shfl_up(s, off);
                if (lane >= off) s += y;
            }
            if (lane < 16) wsum[lane] = s;
        }
        __syncthreads();
        int wofs = (w > 0) ? wsum[w - 1] : 0;
        int incl = carry + wofs + x;
        if (i < n) { rowptr[i + 1] = incl; wo[i] = incl - v; }
        int total = wsum[15];
        __syncthreads();
        carry += total;
    }
    if (t == 0) rowptr[0] = 0;
}

// ---------- fill CSR + precompute per-edge attention logits ----------
// slot p: sidx[p]=src, eidx[p]=edge id, logits[p]=(eh0,eh1,ee0,ee1) pre-lrelu'd
__global__ void fill_kernel(const int* __restrict__ src, const int* __restrict__ dst,
                            const float* __restrict__ er, const float* __restrict__ elh,
                            const float* __restrict__ ele,
                            int* __restrict__ wo, int* __restrict__ sidx,
                            int* __restrict__ eidx, float4* __restrict__ logits, int Nb) {
    int t = blockIdx.x * blockDim.x + threadIdx.x;
    if (t >= Nb) return;
    int d = dst[t], s = src[t];
    int p = atomicAdd(&wo[d], 1);
    float e0 = er[(size_t)d * 2], e1 = er[(size_t)d * 2 + 1];
    float h0 = elh[(size_t)s * 2], h1 = elh[(size_t)s * 2 + 1];
    float l0 = ele[(size_t)t * 2], l1 = ele[(size_t)t * 2 + 1];
    sidx[p] = s;
    eidx[p] = t;
    logits[p] = make_float4(lrelu(h0 + e0), lrelu(h1 + e1), lrelu(l0 + e0), lrelu(l1 + e1));
}

// ---------- aggregation: wave per atom, wave-parallel logits + pipelined row gather ----------
__global__ __launch_bounds__(256) void aggregate(
    const unsigned short* __restrict__ h, const unsigned short* __restrict__ e,
    const unsigned short* __restrict__ u,
    const float* __restrict__ er, const float* __restrict__ elu,
    const int* __restrict__ rowptr, const int* __restrict__ sidx,
    const int* __restrict__ eidx, const float4* __restrict__ logits,
    const int* __restrict__ gid,
    float* __restrict__ hm, int Na)
{
    int wid = (int)((blockIdx.x * (unsigned)blockDim.x + threadIdx.x) >> 6);
    int lane = threadIdx.x & 63;
    if (wid >= Na) return;
    const int a = wid;
    const float er0 = er[(size_t)a * 2], er1 = er[(size_t)a * 2 + 1];
    const int g = gid[a];
    const float eul0 = lrelu(elu[(size_t)g * 2] + er0);
    const float eul1 = lrelu(elu[(size_t)g * 2 + 1] + er1);
    const int rb = rowptr[a], re = rowptr[a + 1];

    // ---- pass A: wave-parallel max over all edge logits ----
    float m0 = eul0, m1 = eul1;
    for (int base = rb; base < re; base += 64) {
        int i = base + lane;
        float lm0 = -1e30f, lm1 = -1e30f;
        if (i < re) {
            float4 lg = logits[i];
            lm0 = fmaxf(lg.x, lg.z);
            lm1 = fmaxf(lg.y, lg.w);
        }
#pragma unroll
        for (int off = 32; off >= 1; off >>= 1) {
            lm0 = fmaxf(lm0, __shfl_xor(lm0, off));
            lm1 = fmaxf(lm1, __shfl_xor(lm1, off));
        }
        m0 = fmaxf(m0, lm0);
        m1 = fmaxf(m1, lm1);
    }

    float es0 = __expf(eul0 - m0), es1 = __expf(eul1 - m1);
    const int head = lane >> 5;
    const int d4 = lane << 2;
    float acc0, acc1, acc2, acc3;
    {
        float eu_sel = head ? es1 : es0;
        ushort4 uv = *(const ushort4*)(u + (size_t)g * 256 + d4);
        acc0 = eu_sel * bf2f(uv.x); acc1 = eu_sel * bf2f(uv.y);
        acc2 = eu_sel * bf2f(uv.z); acc3 = eu_sel * bf2f(uv.w);
    }

    // ---- pass B: exp weights (parallel), then pipelined weighted row gather ----
    for (int base = rb; base < re; base += 64) {
        int n = min(64, re - base);
        float xh0 = 0.f, xh1 = 0.f, xe0 = 0.f, xe1 = 0.f;
        int sv = 0, bv = 0;
        if (lane < n) {
            float4 lg = logits[base + lane];
            xh0 = __expf(lg.x - m0); xh1 = __expf(lg.y - m1);
            xe0 = __expf(lg.z - m0); xe1 = __expf(lg.w - m1);
            sv = sidx[base + lane];
            bv = eidx[base + lane];
        }
        float s0 = xh0 + xe0, s1 = xh1 + xe1;
#pragma unroll
        for (int off = 32; off >= 1; off >>= 1) {
            s0 += __shfl_xor(s0, off);
            s1 += __shfl_xor(s1, off);
        }
        es0 += s0; es1 += s1;

        for (int j = 0; j < n; j++) {
            int s_j = __shfl(sv, j), b_j = __shfl(bv, j);
            float wh0 = __shfl(xh0, j), wh1 = __shfl(xh1, j);
            float we0 = __shfl(xe0, j), we1 = __shfl(xe1, j);
            float wh = head ? wh1 : wh0;
            float we = head ? we1 : we0;
            ushort4 hv = *(const ushort4*)(h + (size_t)s_j * 256 + d4);
            ushort4 ev = *(const ushort4*)(e + (size_t)b_j * 256 + d4);
            acc0 += wh * bf2f(hv.x) + we * bf2f(ev.x);
            acc1 += wh * bf2f(hv.y) + we * bf2f(ev.y);
            acc2 += wh * bf2f(hv.z) + we * bf2f(ev.z);
            acc3 += wh * bf2f(hv.w) + we * bf2f(ev.w);
        }
    }

    float inv = 1.f / (head ? es1 : es0);
    acc0 *= inv; acc1 *= inv; acc2 *= inv; acc3 *= inv;
    // mean over heads: lanes<32 combine with lane+32
    float p0 = __shfl(acc0, (lane + 32) & 63);
    float p1 = __shfl(acc1, (lane + 32) & 63);
    float p2 = __shfl(acc2, (lane + 32) & 63);
    float p3 = __shfl(acc3, (lane + 32) & 63);
    if (lane < 32) {
        float4 o = make_float4(0.5f * (acc0 + p0), 0.5f * (acc1 + p1),
                               0.5f * (acc2 + p2), 0.5f * (acc3 + p3));
        *(float4*)(hm + (size_t)a * 128 + d4) = o;
    }
}

// ---------- BatchNorm stats ----------
__global__ void bnstats(const float* __restrict__ hm, float* __restrict__ sums, int Na) {
    int t = threadIdx.x;
    int c = t & 127, half = t >> 7;
    float s = 0.f, ss = 0.f;
    for (int r = blockIdx.x * 2 + half; r < Na; r += gridDim.x * 2) {
        float v = hm[(size_t)r * 128 + c];
        s += v; ss += v * v;
    }
    atomicAdd(&sums[c], s);
    atomicAdd(&sums[128 + c], ss);
}

// ---------- BN normalize + ReLU ----------
__global__ void bnapply(const float* __restrict__ hm, const float* __restrict__ sums,
                        const float* __restrict__ gamma, const float* __restrict__ beta,
                        float* __restrict__ out, int Na) {
    int t = threadIdx.x;
    int c = t & 127, half = t >> 7;
    float invn = 1.f / (float)Na;
    float mean = sums[c] * invn;
    float var = sums[128 + c] * invn - mean * mean;
    float scale = gamma[c] * rsqrtf(var + 1e-5f);
    float shift = beta[c] - mean * scale;
    for (int r = blockIdx.x * 2 + half; r < Na; r += gridDim.x * 2) {
        float v = hm[(size_t)r * 128 + c] * scale + shift;
        out[(size_t)r * 128 + c] = fmaxf(v, 0.f);
    }
}

// ---------- launch ----------
extern "C" void kernel_launch(void* const* d_in, const int* in_sizes, int n_in,
                              void* d_out, int out_size, void* d_ws, size_t ws_size,
                              hipStream_t stream)
{
    const float* atom   = (const float*)d_in[0];
    const float* bondf  = (const float*)d_in[1];
    const float* globf  = (const float*)d_in[2];
    const float* Wa     = (const float*)d_in[3];
    const float* Wb     = (const float*)d_in[4];
    const float* Wg     = (const float*)d_in[5];
    const float* attn_l = (const float*)d_in[6];
    const float* attn_r = (const float*)d_in[7];
    const float* gamma  = (const float*)d_in[8];
    const float* beta   = (const float*)d_in[9];
    const int* src      = (const int*)d_in[10];
    const int* dst      = (const int*)d_in[11];
    const int* gid      = (const int*)d_in[12];
    const int Na = in_sizes[0] / 128;
    const int Nb = in_sizes[1] / 128;
    const int Ng = in_sizes[2] / 128;

    char* w = (char*)d_ws;
    size_t off = 0;
    auto alloc = [&](size_t bytes) -> void* {
        void* p = w + off;
        off = (off + bytes + 255) & ~(size_t)255;
        return p;
    };
    unsigned short* h   = (unsigned short*)alloc((size_t)Na * 256 * 2);
    unsigned short* e   = (unsigned short*)alloc((size_t)Nb * 256 * 2);
    unsigned short* u   = (unsigned short*)alloc((size_t)Ng * 256 * 2);
    unsigned short* Wpa = (unsigned short*)alloc(32768 * 2);
    unsigned short* Wpb = (unsigned short*)alloc(32768 * 2);
    unsigned short* Wpg = (unsigned short*)alloc(32768 * 2);
    float* er   = (float*)alloc((size_t)Na * 2 * 4);
    float* elh  = (float*)alloc((size_t)Na * 2 * 4);
    float* ele  = (float*)alloc((size_t)Nb * 2 * 4);
    float* elu  = (float*)alloc((size_t)Ng * 2 * 4);
    int* deg    = (int*)alloc((size_t)Na * 4);
    int* rowptr = (int*)alloc((size_t)(Na + 1) * 4);
    int* wo     = (int*)alloc((size_t)Na * 4);
    int* sidx   = (int*)alloc((size_t)Nb * 4);
    int* eidx   = (int*)alloc((size_t)Nb * 4);
    float4* logits = (float4*)alloc((size_t)Nb * 16);
    float* hm   = (float*)alloc((size_t)Na * 128 * 4);
    float* sums = (float*)alloc(256 * 4);

    hipMemsetAsync(deg, 0, (size_t)Na * 4, stream);
    hipMemsetAsync(sums, 0, 256 * 4, stream);

    packW<<<128, 256, 0, stream>>>(Wa, Wpa);
    packW<<<128, 256, 0, stream>>>(Wb, Wpb);
    packW<<<128, 256, 0, stream>>>(Wg, Wpg);

    gemm_mfma<<<(Na + 63) / 64, 256, 0, stream>>>(atom, Wpa, h, Na, attn_l, attn_r, elh, er);
    gemm_mfma<<<(Nb + 63) / 64, 256, 0, stream>>>(bondf, Wpb, e, Nb, attn_l, nullptr, ele, nullptr);
    gemm_mfma<<<(Ng + 63) / 64, 256, 0, stream>>>(globf, Wpg, u, Ng, attn_l, nullptr, elu, nullptr);

    hist_kernel<<<(Nb + 255) / 256, 256, 0, stream>>>(dst, deg, Nb);
    scan1024<<<1, 1024, 0, stream>>>(deg, rowptr, wo, Na);
    fill_kernel<<<(Nb + 255) / 256, 256, 0, stream>>>(src, dst, er, elh, ele,
                                                      wo, sidx, eidx, logits, Nb);

    aggregate<<<(Na + 3) / 4, 256, 0, stream>>>(h, e, u, er, elu,
                                                rowptr, sidx, eidx, logits, gid, hm, Na);
    bnstats<<<256, 256, 0, stream>>>(hm, sums, Na);
    bnapply<<<512, 256, 0, stream>>>(hm, sums, gamma, beta, (float*)d_out, Na);
}